// Round 2
// baseline (261.106 us; speedup 1.0000x reference)
//
#include <hip/hip_runtime.h>

#define B_ 4
#define S_ 2048
#define E_ 1024

typedef __attribute__((ext_vector_type(8))) short short8;
typedef __attribute__((ext_vector_type(4))) float f32x4;

__device__ __forceinline__ unsigned short f2bu(float f) {
  unsigned u = __builtin_bit_cast(unsigned, f);
  u = (u + 0x7FFFu + ((u >> 16) & 1u)) >> 16;
  return (unsigned short)u;
}

__device__ __forceinline__ void gload_lds16(const void* g, void* l) {
  __builtin_amdgcn_global_load_lds(
      (const __attribute__((address_space(1))) void*)g,
      (__attribute__((address_space(3))) void*)l, 16, 0, 0);
}

// ---------------- fp32 -> bf16 convert ----------------
__global__ __launch_bounds__(256) void cvt_f32_bf16(
    const float* __restrict__ in, unsigned short* __restrict__ out, int n) {
  int i = blockIdx.x * 256 + threadIdx.x;
  if (i * 4 >= n) return;
  float4 v = ((const float4*)in)[i];
  ushort4 o;
  o.x = f2bu(v.x); o.y = f2bu(v.y); o.z = f2bu(v.z); o.w = f2bu(v.w);
  ((ushort4*)out)[i] = o;
}

// ---------------- B^T GEMM, m97 structure, 3 modes ----------------
// MODE 0 (QKV):   A=xb(8192x1024), B=[Wq;Wk;Wv](3072x1024 contiguous bf16).
//                 grid (24,64,1). seg=bn>>3: 0->Q rowmajor, 1->K rowmajor,
//                 2->V transposed [E][B*S]. bias per seg.
// MODE 1 (SCORES):lower-tri linear grid (136,1,4); fp32 out, scale=1/32.
// MODE 2 (PV):    A=P bf16 rows (stride 2*S_ elems within fp32 buffer),
//                 B=Vt(1024x8192), Keff=(bm+1)*128, fp32 out. grid (8,16,4).
template<int MODE>
__global__ __launch_bounds__(256, 5) void gemm_bt(
    const unsigned short* __restrict__ A, long sAz, int lda,
    const unsigned short* __restrict__ B, long sBz, int ldb,
    const float* __restrict__ bias0, const float* __restrict__ bias1,
    const float* __restrict__ bias2,
    void* __restrict__ C0, void* __restrict__ C1, void* __restrict__ C2,
    long sCz, int ldc, int K, float scale) {
  constexpr int BM = 128, BN = 128, BK = 64;
  __shared__ unsigned short lA[BM * BK];
  __shared__ unsigned short lB[BN * BK];
  int bm, bn;
  int bz = blockIdx.z;
  if constexpr (MODE == 1) {
    int t = blockIdx.x;  // 0..135 lower-tri linear
    bm = (int)((sqrtf(8.f * t + 1.f) - 1.f) * 0.5f);
    while ((bm + 1) * (bm + 2) / 2 <= t) bm++;
    while (bm * (bm + 1) / 2 > t) bm--;
    bn = t - bm * (bm + 1) / 2;
  } else {
    bm = blockIdx.y; bn = blockIdx.x;
  }
  const unsigned short* Ab = A + (long)bz * sAz + (long)bm * BM * lda;
  const unsigned short* Bb = B + (long)bz * sBz + (long)bn * BN * ldb;
  int Keff = (MODE == 2) ? min(K, (bm + 1) * BM) : K;

  int tid = threadIdx.x;
  int l = tid & 63, w = tid >> 6;
  int wm = w >> 1, wn = w & 1;  // wave computes 64x64 at (wm*64, wn*64)

  // staging: per K-step each 16KB tile = 16 chunks of 1KB (64 lanes x 16B)
  int srow = l >> 3;
  int schunk = (l & 7) * 8;
  const unsigned short* ga[4];
  const unsigned short* gb[4];
  unsigned short* lad[4];
  unsigned short* lbd[4];
#pragma unroll
  for (int i = 0; i < 4; i++) {
    int seg = i * 4 + w;
    int row = seg * 8 + srow;
    ga[i] = Ab + (long)row * lda + schunk;
    gb[i] = Bb + (long)row * ldb + schunk;
    lad[i] = &lA[seg * 512];
    lbd[i] = &lB[seg * 512];
  }
  int aoff[4], boff[4];
#pragma unroll
  for (int i = 0; i < 4; i++) {
    aoff[i] = (wm * 64 + i * 16 + (l & 15)) * BK + (l >> 4) * 8;
    boff[i] = (wn * 64 + i * 16 + (l & 15)) * BK + (l >> 4) * 8;
  }

  f32x4 acc[4][4] = {};
  for (int k0 = 0; k0 < Keff; k0 += BK) {
    __syncthreads();
#pragma unroll
    for (int i = 0; i < 4; i++) {
      gload_lds16(ga[i], lad[i]);
      gload_lds16(gb[i], lbd[i]);
    }
#pragma unroll
    for (int i = 0; i < 4; i++) { ga[i] += BK; gb[i] += BK; }
    __syncthreads();
#pragma unroll
    for (int kk = 0; kk < 2; kk++) {
      short8 af[4], bf[4];
#pragma unroll
      for (int i = 0; i < 4; i++) af[i] = *(const short8*)&lA[aoff[i] + kk * 32];
#pragma unroll
      for (int j = 0; j < 4; j++) bf[j] = *(const short8*)&lB[boff[j] + kk * 32];
#pragma unroll
      for (int i = 0; i < 4; i++)
#pragma unroll
        for (int j = 0; j < 4; j++)
          acc[i][j] = __builtin_amdgcn_mfma_f32_16x16x32_bf16(af[i], bf[j], acc[i][j], 0, 0, 0);
    }
  }

  // epilogue: D col = lane&15, row = (lane>>4)*4 + t   [m89-verified]
  int rh = l >> 4, cl = l & 15;
  long rowbase = (long)bm * BM + wm * 64 + rh * 4;
  int colbase = bn * BN + wn * 64 + cl;

  if constexpr (MODE == 0) {
    int seg = bn >> 3;  // wave-uniform: 0=Q 1=K 2=V
    const float* bias = (seg == 0) ? bias0 : (seg == 1) ? bias1 : bias2;
#pragma unroll
    for (int j = 0; j < 4; j++) {
      int c = colbase + j * 16;
      int cl_ = c & 1023;
      float bv_ = bias[cl_];
#pragma unroll
      for (int i = 0; i < 4; i++) {
        long r0 = rowbase + i * 16;
        f32x4 v = acc[i][j];
        if (seg < 2) {
          unsigned short* Ch = (unsigned short*)((seg == 0) ? C0 : C1);
#pragma unroll
          for (int t = 0; t < 4; t++)
            Ch[(r0 + t) * (long)E_ + cl_] = f2bu(v[t] + bv_);
        } else {
          unsigned short* Vt = (unsigned short*)C2;
          ushort4 pk;
          pk.x = f2bu(v[0] + bv_);
          pk.y = f2bu(v[1] + bv_);
          pk.z = f2bu(v[2] + bv_);
          pk.w = f2bu(v[3] + bv_);
          *(ushort4*)(Vt + (long)cl_ * (B_ * S_) + r0) = pk;
        }
      }
    }
  } else {
    float* Cf = (float*)C0 + (long)bz * sCz;
#pragma unroll
    for (int j = 0; j < 4; j++) {
      int c = colbase + j * 16;
#pragma unroll
      for (int i = 0; i < 4; i++) {
        long r0 = rowbase + i * 16;
        f32x4 v = acc[i][j];
#pragma unroll
        for (int t = 0; t < 4; t++)
          Cf[(r0 + t) * (long)ldc + c] = v[t] * scale;
      }
    }
  }
}

// ---------------- causal row softmax, fp32 scores -> bf16 P in place ----------------
__global__ __launch_bounds__(256) void softmax_kernel(float* __restrict__ scores) {
  long r = blockIdx.x;
  int q = (int)(r & (S_ - 1));
  float* row = scores + r * (long)S_;
  int n = q + 1;
  int tid = threadIdx.x;

  float vv[8];
  float m = -1e30f;
  const float4* row4 = (const float4*)row;
#pragma unroll
  for (int i = 0; i < 2; i++) {
    int idx = tid + i * 256;
    float4 f = row4[idx];
    int kb = idx * 4;
    vv[i * 4 + 0] = (kb + 0 < n) ? f.x : -1e30f;
    vv[i * 4 + 1] = (kb + 1 < n) ? f.y : -1e30f;
    vv[i * 4 + 2] = (kb + 2 < n) ? f.z : -1e30f;
    vv[i * 4 + 3] = (kb + 3 < n) ? f.w : -1e30f;
  }
#pragma unroll
  for (int i = 0; i < 8; i++) m = fmaxf(m, vv[i]);
#pragma unroll
  for (int o = 32; o > 0; o >>= 1) m = fmaxf(m, __shfl_xor(m, o));
  __shared__ float red[8];
  int wv = tid >> 6, ln = tid & 63;
  if (ln == 0) red[wv] = m;
  __syncthreads();
  m = fmaxf(fmaxf(red[0], red[1]), fmaxf(red[2], red[3]));

  float s = 0.f;
#pragma unroll
  for (int i = 0; i < 8; i++) { vv[i] = __expf(vv[i] - m); s += vv[i]; }
#pragma unroll
  for (int o = 32; o > 0; o >>= 1) s += __shfl_xor(s, o);
  if (ln == 0) red[4 + wv] = s;
  __syncthreads();
  s = red[4] + red[5] + red[6] + red[7];
  float inv = 1.f / s;

  unsigned short* prow = (unsigned short*)row;
  int nfill = ((q >> 7) + 1) << 7;
#pragma unroll
  for (int i = 0; i < 2; i++) {
    int kb = (tid + i * 256) * 4;
    if (kb < nfill) {
      ushort4 o;
      o.x = f2bu(vv[i * 4 + 0] * inv);
      o.y = f2bu(vv[i * 4 + 1] * inv);
      o.z = f2bu(vv[i * 4 + 2] * inv);
      o.w = f2bu(vv[i * 4 + 3] * inv);
      *(ushort4*)(prow + kb) = o;
    }
  }
}

// ---------------- host ----------------
extern "C" void kernel_launch(void* const* d_in, const int* in_sizes, int n_in,
                              void* d_out, int out_size, void* d_ws, size_t ws_size,
                              hipStream_t stream) {
  const float* x  = (const float*)d_in[0];
  const float* Wq = (const float*)d_in[2];
  const float* bq = (const float*)d_in[3];
  const float* Wk = (const float*)d_in[4];
  const float* bk = (const float*)d_in[5];
  const float* Wv = (const float*)d_in[6];
  const float* bv = (const float*)d_in[7];
  float* out = (float*)d_out;

  const long NX = (long)B_ * S_ * E_;  // 8388608
  const long NW = (long)E_ * E_;       // 1048576
  unsigned short* xb  = (unsigned short*)d_ws;
  unsigned short* wqb = xb + NX;       // [3072][1024] contiguous (q,k,v)
  unsigned short* wkb = wqb + NW;
  unsigned short* wvb = wkb + NW;
  unsigned short* Qb  = wvb + NW;
  unsigned short* Kb  = Qb + NX;
  unsigned short* Vtb = Kb + NX;            // layout [E][B*S]
  float* scores = (float*)(Vtb + NX);       // [B][S][S] fp32, P bf16 in place

  cvt_f32_bf16<<<8192, 256, 0, stream>>>(x, xb, (int)NX);
  cvt_f32_bf16<<<1024, 256, 0, stream>>>(Wq, wqb, (int)NW);
  cvt_f32_bf16<<<1024, 256, 0, stream>>>(Wk, wkb, (int)NW);
  cvt_f32_bf16<<<1024, 256, 0, stream>>>(Wv, wvb, (int)NW);

  // fused QKV: A=xb, B=[Wq;Wk;Wv] (3072x1024), N=3072
  gemm_bt<0><<<dim3(24, 64, 1), 256, 0, stream>>>(
      xb, 0, E_, wqb, 0, E_, bq, bk, bv,
      Qb, Kb, Vtb, 0, E_, E_, 1.f);

  // scores = Q K^T / 32, lower-tri linear grid
  gemm_bt<1><<<dim3(136, 1, 4), 256, 0, stream>>>(
      Qb, (long)S_ * E_, E_, Kb, (long)S_ * E_, E_, nullptr, nullptr, nullptr,
      scores, nullptr, nullptr, (long)S_ * S_, S_, E_, 0.03125f);

  softmax_kernel<<<B_ * S_, 256, 0, stream>>>(scores);

  // out = P V : A = P (bf16 rows at stride 2*S elements), B = Vt (N=E, K=S)
  gemm_bt<2><<<dim3(8, 16, 4), 256, 0, stream>>>(
      (const unsigned short*)scores, (long)S_ * S_ * 2, 2 * S_,
      Vtb, (long)S_, B_ * S_, nullptr, nullptr, nullptr,
      out, nullptr, nullptr, (long)S_ * E_, E_, S_, 1.f);
}

// Round 3
// 186.313 us; speedup vs baseline: 1.4014x; 1.4014x over previous
//
#include <hip/hip_runtime.h>

#define B_ 4
#define S_ 2048
#define E_ 1024

typedef __attribute__((ext_vector_type(8))) short short8;
typedef __attribute__((ext_vector_type(4))) float f32x4;

__device__ __forceinline__ unsigned short f2bu(float f) {
  unsigned u = __builtin_bit_cast(unsigned, f);
  u = (u + 0x7FFFu + ((u >> 16) & 1u)) >> 16;
  return (unsigned short)u;
}

__device__ __forceinline__ void gload_lds16(const void* g, void* l) {
  __builtin_amdgcn_global_load_lds(
      (const __attribute__((address_space(1))) void*)g,
      (__attribute__((address_space(3))) void*)l, 16, 0, 0);
}

// ---------------- fp32 -> bf16 convert ----------------
__global__ __launch_bounds__(256) void cvt_f32_bf16(
    const float* __restrict__ in, unsigned short* __restrict__ out, int n) {
  int i = blockIdx.x * 256 + threadIdx.x;
  if (i * 4 >= n) return;
  float4 v = ((const float4*)in)[i];
  ushort4 o;
  o.x = f2bu(v.x); o.y = f2bu(v.y); o.z = f2bu(v.z); o.w = f2bu(v.w);
  ((ushort4*)out)[i] = o;
}

// ---------------- B^T GEMM, m97 structure, 3 modes ----------------
// MODE 0 (QKV):   A=xb(8192x1024), B=[Wq;Wk;Wv](3072x1024 contiguous bf16).
//                 grid (24,64,1). seg=bn>>3: 0->Q rowmajor, 1->K rowmajor,
//                 2->V transposed [E][B*S]. bias per seg.
// MODE 1 (SCORES):lower-tri linear grid (136,1,4); fp32 out, scale=1/32.
// MODE 2 (PV):    A=P bf16 rows (stride 2*S_ elems within fp32 buffer),
//                 B=Vt(1024x8192), Keff=(bm+1)*128, fp32 out. grid (8,16,4).
template<int MODE>
__global__ __launch_bounds__(256, 3) void gemm_bt(
    const unsigned short* __restrict__ A, long sAz, int lda,
    const unsigned short* __restrict__ B, long sBz, int ldb,
    const float* __restrict__ bias0, const float* __restrict__ bias1,
    const float* __restrict__ bias2,
    void* __restrict__ C0, void* __restrict__ C1, void* __restrict__ C2,
    long sCz, int ldc, int K, float scale) {
  constexpr int BM = 128, BN = 128, BK = 64;
  __shared__ unsigned short lA[BM * BK];
  __shared__ unsigned short lB[BN * BK];
  int bm, bn;
  int bz = blockIdx.z;
  if constexpr (MODE == 1) {
    int t = blockIdx.x;  // 0..135 lower-tri linear
    bm = (int)((sqrtf(8.f * t + 1.f) - 1.f) * 0.5f);
    while ((bm + 1) * (bm + 2) / 2 <= t) bm++;
    while (bm * (bm + 1) / 2 > t) bm--;
    bn = t - bm * (bm + 1) / 2;
  } else {
    bm = blockIdx.y; bn = blockIdx.x;
  }
  const unsigned short* Ab = A + (long)bz * sAz + (long)bm * BM * lda;
  const unsigned short* Bb = B + (long)bz * sBz + (long)bn * BN * ldb;
  int Keff = (MODE == 2) ? min(K, (bm + 1) * BM) : K;

  int tid = threadIdx.x;
  int l = tid & 63, w = tid >> 6;
  int wm = w >> 1, wn = w & 1;  // wave computes 64x64 at (wm*64, wn*64)

  // staging: per K-step each 16KB tile = 16 chunks of 1KB (64 lanes x 16B)
  int srow = l >> 3;
  int schunk = (l & 7) * 8;
  const unsigned short* ga[4];
  const unsigned short* gb[4];
  unsigned short* lad[4];
  unsigned short* lbd[4];
#pragma unroll
  for (int i = 0; i < 4; i++) {
    int seg = i * 4 + w;
    int row = seg * 8 + srow;
    ga[i] = Ab + (long)row * lda + schunk;
    gb[i] = Bb + (long)row * ldb + schunk;
    lad[i] = &lA[seg * 512];
    lbd[i] = &lB[seg * 512];
  }
  int aoff[4], boff[4];
#pragma unroll
  for (int i = 0; i < 4; i++) {
    aoff[i] = (wm * 64 + i * 16 + (l & 15)) * BK + (l >> 4) * 8;
    boff[i] = (wn * 64 + i * 16 + (l & 15)) * BK + (l >> 4) * 8;
  }

  f32x4 acc[4][4] = {};
  for (int k0 = 0; k0 < Keff; k0 += BK) {
    __syncthreads();
#pragma unroll
    for (int i = 0; i < 4; i++) {
      gload_lds16(ga[i], lad[i]);
      gload_lds16(gb[i], lbd[i]);
    }
#pragma unroll
    for (int i = 0; i < 4; i++) { ga[i] += BK; gb[i] += BK; }
    __syncthreads();
#pragma unroll
    for (int kk = 0; kk < 2; kk++) {
      short8 af[4], bf[4];
#pragma unroll
      for (int i = 0; i < 4; i++) af[i] = *(const short8*)&lA[aoff[i] + kk * 32];
#pragma unroll
      for (int j = 0; j < 4; j++) bf[j] = *(const short8*)&lB[boff[j] + kk * 32];
#pragma unroll
      for (int i = 0; i < 4; i++)
#pragma unroll
        for (int j = 0; j < 4; j++)
          acc[i][j] = __builtin_amdgcn_mfma_f32_16x16x32_bf16(af[i], bf[j], acc[i][j], 0, 0, 0);
    }
  }

  // epilogue: D col = lane&15, row = (lane>>4)*4 + t   [m89-verified]
  int rh = l >> 4, cl = l & 15;
  long rowbase = (long)bm * BM + wm * 64 + rh * 4;
  int colbase = bn * BN + wn * 64 + cl;

  if constexpr (MODE == 0) {
    int seg = bn >> 3;  // wave-uniform: 0=Q 1=K 2=V
    const float* bias = (seg == 0) ? bias0 : (seg == 1) ? bias1 : bias2;
#pragma unroll
    for (int j = 0; j < 4; j++) {
      int c = colbase + j * 16;
      int cl_ = c & 1023;
      float bv_ = bias[cl_];
#pragma unroll
      for (int i = 0; i < 4; i++) {
        long r0 = rowbase + i * 16;
        f32x4 v = acc[i][j];
        if (seg < 2) {
          unsigned short* Ch = (unsigned short*)((seg == 0) ? C0 : C1);
#pragma unroll
          for (int t = 0; t < 4; t++)
            Ch[(r0 + t) * (long)E_ + cl_] = f2bu(v[t] + bv_);
        } else {
          unsigned short* Vt = (unsigned short*)C2;
          ushort4 pk;
          pk.x = f2bu(v[0] + bv_);
          pk.y = f2bu(v[1] + bv_);
          pk.z = f2bu(v[2] + bv_);
          pk.w = f2bu(v[3] + bv_);
          *(ushort4*)(Vt + (long)cl_ * (B_ * S_) + r0) = pk;
        }
      }
    }
  } else {
    float* Cf = (float*)C0 + (long)bz * sCz;
#pragma unroll
    for (int j = 0; j < 4; j++) {
      int c = colbase + j * 16;
#pragma unroll
      for (int i = 0; i < 4; i++) {
        long r0 = rowbase + i * 16;
        f32x4 v = acc[i][j];
#pragma unroll
        for (int t = 0; t < 4; t++)
          Cf[(r0 + t) * (long)ldc + c] = v[t] * scale;
      }
    }
  }
}

// ---------------- causal row softmax, fp32 scores -> bf16 P in place ----------------
__global__ __launch_bounds__(256) void softmax_kernel(float* __restrict__ scores) {
  long r = blockIdx.x;
  int q = (int)(r & (S_ - 1));
  float* row = scores + r * (long)S_;
  int n = q + 1;
  int tid = threadIdx.x;

  float vv[8];
  float m = -1e30f;
  const float4* row4 = (const float4*)row;
#pragma unroll
  for (int i = 0; i < 2; i++) {
    int idx = tid + i * 256;
    float4 f = row4[idx];
    int kb = idx * 4;
    vv[i * 4 + 0] = (kb + 0 < n) ? f.x : -1e30f;
    vv[i * 4 + 1] = (kb + 1 < n) ? f.y : -1e30f;
    vv[i * 4 + 2] = (kb + 2 < n) ? f.z : -1e30f;
    vv[i * 4 + 3] = (kb + 3 < n) ? f.w : -1e30f;
  }
#pragma unroll
  for (int i = 0; i < 8; i++) m = fmaxf(m, vv[i]);
#pragma unroll
  for (int o = 32; o > 0; o >>= 1) m = fmaxf(m, __shfl_xor(m, o));
  __shared__ float red[8];
  int wv = tid >> 6, ln = tid & 63;
  if (ln == 0) red[wv] = m;
  __syncthreads();
  m = fmaxf(fmaxf(red[0], red[1]), fmaxf(red[2], red[3]));

  float s = 0.f;
#pragma unroll
  for (int i = 0; i < 8; i++) { vv[i] = __expf(vv[i] - m); s += vv[i]; }
#pragma unroll
  for (int o = 32; o > 0; o >>= 1) s += __shfl_xor(s, o);
  if (ln == 0) red[4 + wv] = s;
  __syncthreads();
  s = red[4] + red[5] + red[6] + red[7];
  float inv = 1.f / s;

  unsigned short* prow = (unsigned short*)row;
  int nfill = ((q >> 7) + 1) << 7;
#pragma unroll
  for (int i = 0; i < 2; i++) {
    int kb = (tid + i * 256) * 4;
    if (kb < nfill) {
      ushort4 o;
      o.x = f2bu(vv[i * 4 + 0] * inv);
      o.y = f2bu(vv[i * 4 + 1] * inv);
      o.z = f2bu(vv[i * 4 + 2] * inv);
      o.w = f2bu(vv[i * 4 + 3] * inv);
      *(ushort4*)(prow + kb) = o;
    }
  }
}

// ---------------- host ----------------
extern "C" void kernel_launch(void* const* d_in, const int* in_sizes, int n_in,
                              void* d_out, int out_size, void* d_ws, size_t ws_size,
                              hipStream_t stream) {
  const float* x  = (const float*)d_in[0];
  const float* Wq = (const float*)d_in[2];
  const float* bq = (const float*)d_in[3];
  const float* Wk = (const float*)d_in[4];
  const float* bk = (const float*)d_in[5];
  const float* Wv = (const float*)d_in[6];
  const float* bv = (const float*)d_in[7];
  float* out = (float*)d_out;

  const long NX = (long)B_ * S_ * E_;  // 8388608
  const long NW = (long)E_ * E_;       // 1048576
  unsigned short* xb  = (unsigned short*)d_ws;
  unsigned short* wqb = xb + NX;       // [3072][1024] contiguous (q,k,v)
  unsigned short* wkb = wqb + NW;
  unsigned short* wvb = wkb + NW;
  unsigned short* Qb  = wvb + NW;
  unsigned short* Kb  = Qb + NX;
  unsigned short* Vtb = Kb + NX;            // layout [E][B*S]
  float* scores = (float*)(Vtb + NX);       // [B][S][S] fp32, P bf16 in place

  cvt_f32_bf16<<<8192, 256, 0, stream>>>(x, xb, (int)NX);
  cvt_f32_bf16<<<1024, 256, 0, stream>>>(Wq, wqb, (int)NW);
  cvt_f32_bf16<<<1024, 256, 0, stream>>>(Wk, wkb, (int)NW);
  cvt_f32_bf16<<<1024, 256, 0, stream>>>(Wv, wvb, (int)NW);

  // fused QKV: A=xb, B=[Wq;Wk;Wv] (3072x1024), N=3072
  gemm_bt<0><<<dim3(24, 64, 1), 256, 0, stream>>>(
      xb, 0, E_, wqb, 0, E_, bq, bk, bv,
      Qb, Kb, Vtb, 0, E_, E_, 1.f);

  // scores = Q K^T / 32, lower-tri linear grid
  gemm_bt<1><<<dim3(136, 1, 4), 256, 0, stream>>>(
      Qb, (long)S_ * E_, E_, Kb, (long)S_ * E_, E_, nullptr, nullptr, nullptr,
      scores, nullptr, nullptr, (long)S_ * S_, S_, E_, 0.03125f);

  softmax_kernel<<<B_ * S_, 256, 0, stream>>>(scores);

  // out = P V : A = P (bf16 rows at stride 2*S elements), B = Vt (N=E, K=S)
  gemm_bt<2><<<dim3(8, 16, 4), 256, 0, stream>>>(
      (const unsigned short*)scores, (long)S_ * S_ * 2, 2 * S_,
      Vtb, (long)S_, B_ * S_, nullptr, nullptr, nullptr,
      out, nullptr, nullptr, (long)S_ * E_, E_, S_, 1.f);
}

// Round 4
// 175.033 us; speedup vs baseline: 1.4918x; 1.0644x over previous
//
#include <hip/hip_runtime.h>

#define B_ 4
#define S_ 2048
#define E_ 1024

typedef __attribute__((ext_vector_type(8))) short short8;
typedef __attribute__((ext_vector_type(4))) float f32x4;

__device__ __forceinline__ unsigned short f2bu(float f) {
  unsigned u = __builtin_bit_cast(unsigned, f);
  u = (u + 0x7FFFu + ((u >> 16) & 1u)) >> 16;
  return (unsigned short)u;
}

__device__ __forceinline__ void gload_lds16(const void* g, void* l) {
  __builtin_amdgcn_global_load_lds(
      (const __attribute__((address_space(1))) void*)g,
      (__attribute__((address_space(3))) void*)l, 16, 0, 0);
}

// ---------------- fp32 -> bf16 convert ----------------
__global__ __launch_bounds__(256) void cvt_f32_bf16(
    const float* __restrict__ in, unsigned short* __restrict__ out, int n) {
  int i = blockIdx.x * 256 + threadIdx.x;
  if (i * 4 >= n) return;
  float4 v = ((const float4*)in)[i];
  ushort4 o;
  o.x = f2bu(v.x); o.y = f2bu(v.y); o.z = f2bu(v.z); o.w = f2bu(v.w);
  ((ushort4*)out)[i] = o;
}

// three weight matrices in one dispatch (z selects)
__global__ __launch_bounds__(256) void cvt_w3(
    const float* __restrict__ w0, const float* __restrict__ w1,
    const float* __restrict__ w2, unsigned short* __restrict__ out, int n) {
  int z = blockIdx.z;
  const float* in = (z == 0) ? w0 : (z == 1) ? w1 : w2;
  int i = blockIdx.x * 256 + threadIdx.x;
  if (i * 4 >= n) return;
  float4 v = ((const float4*)in)[i];
  ushort4 o;
  o.x = f2bu(v.x); o.y = f2bu(v.y); o.z = f2bu(v.z); o.w = f2bu(v.w);
  ((ushort4*)(out + (long)z * n))[i] = o;
}

// ---------------- B^T GEMM, m97 structure, 3 modes ----------------
// MODE 0 (QKV):   A=xb(8192x1024), B=[Wq;Wk;Wv](3072x1024 contiguous bf16).
//                 grid (24,64,1). seg=bn>>3: 0->Q rowmajor, 1->K rowmajor,
//                 2->V transposed [E][B*S]. bias per seg.
// MODE 1 (SCORES+EXP): lower-tri linear grid (136,1,4); epilogue writes
//                 P' = exp(s/32) bf16 (c<=r else 0) to C0 (lda S_). No softmax pass.
// MODE 2 (PV+NORM): A=P' bf16 (lda S_), B=Vt(1024x8192), Keff=(bm+1)*128.
//                 Extra all-ones B-frag accumulates row denom; epilogue divides.
template<int MODE>
__global__ __launch_bounds__(256, 3) void gemm_bt(
    const unsigned short* __restrict__ A, long sAz, int lda,
    const unsigned short* __restrict__ B, long sBz, int ldb,
    const float* __restrict__ bias0, const float* __restrict__ bias1,
    const float* __restrict__ bias2,
    void* __restrict__ C0, void* __restrict__ C1, void* __restrict__ C2,
    long sCz, int ldc, int K, float scale) {
  constexpr int BM = 128, BN = 128, BK = 64;
  __shared__ unsigned short lA[BM * BK];
  __shared__ unsigned short lB[BN * BK];
  int bm, bn;
  int bz = blockIdx.z;
  if constexpr (MODE == 1) {
    int t = blockIdx.x;  // 0..135 lower-tri linear
    bm = (int)((sqrtf(8.f * t + 1.f) - 1.f) * 0.5f);
    while ((bm + 1) * (bm + 2) / 2 <= t) bm++;
    while (bm * (bm + 1) / 2 > t) bm--;
    bn = t - bm * (bm + 1) / 2;
  } else {
    bm = blockIdx.y; bn = blockIdx.x;
  }
  const unsigned short* Ab = A + (long)bz * sAz + (long)bm * BM * lda;
  const unsigned short* Bb = B + (long)bz * sBz + (long)bn * BN * ldb;
  int Keff = (MODE == 2) ? min(K, (bm + 1) * BM) : K;

  int tid = threadIdx.x;
  int l = tid & 63, w = tid >> 6;
  int wm = w >> 1, wn = w & 1;  // wave computes 64x64 at (wm*64, wn*64)

  // staging: per K-step each 16KB tile = 16 chunks of 1KB (64 lanes x 16B)
  int srow = l >> 3;
  int schunk = (l & 7) * 8;
  const unsigned short* ga[4];
  const unsigned short* gb[4];
  unsigned short* lad[4];
  unsigned short* lbd[4];
#pragma unroll
  for (int i = 0; i < 4; i++) {
    int seg = i * 4 + w;
    int row = seg * 8 + srow;
    ga[i] = Ab + (long)row * lda + schunk;
    gb[i] = Bb + (long)row * ldb + schunk;
    lad[i] = &lA[seg * 512];
    lbd[i] = &lB[seg * 512];
  }
  int aoff[4], boff[4];
#pragma unroll
  for (int i = 0; i < 4; i++) {
    aoff[i] = (wm * 64 + i * 16 + (l & 15)) * BK + (l >> 4) * 8;
    boff[i] = (wn * 64 + i * 16 + (l & 15)) * BK + (l >> 4) * 8;
  }

  f32x4 acc[4][4] = {};
  f32x4 accd[4] = {};  // MODE 2: row-sum (denominator) via all-ones B
  short8 ones;
#pragma unroll
  for (int z = 0; z < 8; z++) ones[z] = (short)0x3F80;  // bf16 1.0

  for (int k0 = 0; k0 < Keff; k0 += BK) {
    __syncthreads();
#pragma unroll
    for (int i = 0; i < 4; i++) {
      gload_lds16(ga[i], lad[i]);
      gload_lds16(gb[i], lbd[i]);
    }
#pragma unroll
    for (int i = 0; i < 4; i++) { ga[i] += BK; gb[i] += BK; }
    __syncthreads();
#pragma unroll
    for (int kk = 0; kk < 2; kk++) {
      short8 af[4], bf[4];
#pragma unroll
      for (int i = 0; i < 4; i++) af[i] = *(const short8*)&lA[aoff[i] + kk * 32];
#pragma unroll
      for (int j = 0; j < 4; j++) bf[j] = *(const short8*)&lB[boff[j] + kk * 32];
#pragma unroll
      for (int i = 0; i < 4; i++)
#pragma unroll
        for (int j = 0; j < 4; j++)
          acc[i][j] = __builtin_amdgcn_mfma_f32_16x16x32_bf16(af[i], bf[j], acc[i][j], 0, 0, 0);
      if constexpr (MODE == 2) {
#pragma unroll
        for (int i = 0; i < 4; i++)
          accd[i] = __builtin_amdgcn_mfma_f32_16x16x32_bf16(af[i], ones, accd[i], 0, 0, 0);
      }
    }
  }

  // epilogue: D col = lane&15, row = (lane>>4)*4 + t   [m89-verified]
  int rh = l >> 4, cl = l & 15;
  long rowbase = (long)bm * BM + wm * 64 + rh * 4;
  int colbase = bn * BN + wn * 64 + cl;

  if constexpr (MODE == 0) {
    int seg = bn >> 3;  // wave-uniform: 0=Q 1=K 2=V
    const float* bias = (seg == 0) ? bias0 : (seg == 1) ? bias1 : bias2;
#pragma unroll
    for (int j = 0; j < 4; j++) {
      int c = colbase + j * 16;
      int cl_ = c & 1023;
      float bv_ = bias[cl_];
#pragma unroll
      for (int i = 0; i < 4; i++) {
        long r0 = rowbase + i * 16;
        f32x4 v = acc[i][j];
        if (seg < 2) {
          unsigned short* Ch = (unsigned short*)((seg == 0) ? C0 : C1);
#pragma unroll
          for (int t = 0; t < 4; t++)
            Ch[(r0 + t) * (long)E_ + cl_] = f2bu(v[t] + bv_);
        } else {
          unsigned short* Vt = (unsigned short*)C2;
          ushort4 pk;
          pk.x = f2bu(v[0] + bv_);
          pk.y = f2bu(v[1] + bv_);
          pk.z = f2bu(v[2] + bv_);
          pk.w = f2bu(v[3] + bv_);
          *(ushort4*)(Vt + (long)cl_ * (B_ * S_) + r0) = pk;
        }
      }
    }
  } else if constexpr (MODE == 1) {
    // P' = exp(s * scale), causal-masked, bf16
    unsigned short* Ph = (unsigned short*)C0 + (long)bz * sCz;
#pragma unroll
    for (int j = 0; j < 4; j++) {
      int c = colbase + j * 16;
#pragma unroll
      for (int i = 0; i < 4; i++) {
        int r0 = (int)rowbase + i * 16;
        f32x4 v = acc[i][j];
#pragma unroll
        for (int t = 0; t < 4; t++) {
          int r = r0 + t;
          float p = (c <= r) ? __expf(v[t] * scale) : 0.f;
          Ph[(long)r * ldc + c] = f2bu(p);
        }
      }
    }
  } else {
    // out = acc / denom
    float* Cf = (float*)C0 + (long)bz * sCz;
#pragma unroll
    for (int j = 0; j < 4; j++) {
      int c = colbase + j * 16;
#pragma unroll
      for (int i = 0; i < 4; i++) {
        long r0 = rowbase + i * 16;
        f32x4 v = acc[i][j];
        f32x4 d = accd[i];
#pragma unroll
        for (int t = 0; t < 4; t++)
          Cf[(r0 + t) * (long)ldc + c] = v[t] / d[t];
      }
    }
  }
}

// ---------------- host ----------------
extern "C" void kernel_launch(void* const* d_in, const int* in_sizes, int n_in,
                              void* d_out, int out_size, void* d_ws, size_t ws_size,
                              hipStream_t stream) {
  const float* x  = (const float*)d_in[0];
  const float* Wq = (const float*)d_in[2];
  const float* bq = (const float*)d_in[3];
  const float* Wk = (const float*)d_in[4];
  const float* bk = (const float*)d_in[5];
  const float* Wv = (const float*)d_in[6];
  const float* bv = (const float*)d_in[7];
  float* out = (float*)d_out;

  const long NX = (long)B_ * S_ * E_;  // 8388608
  const long NW = (long)E_ * E_;       // 1048576
  unsigned short* xb  = (unsigned short*)d_ws;
  unsigned short* wqb = xb + NX;       // [3072][1024] contiguous (q,k,v)
  unsigned short* Qb  = wqb + 3 * NW;
  unsigned short* Kb  = Qb + NX;
  unsigned short* Vtb = Kb + NX;       // layout [E][B*S]
  unsigned short* Pb  = Vtb + NX;      // [B][S][S] bf16 unnormalized exp-scores

  cvt_f32_bf16<<<8192, 256, 0, stream>>>(x, xb, (int)NX);
  cvt_w3<<<dim3(1024, 1, 3), 256, 0, stream>>>(Wq, Wk, Wv, wqb, (int)NW);

  // fused QKV: A=xb, B=[Wq;Wk;Wv] (3072x1024), N=3072
  gemm_bt<0><<<dim3(24, 64, 1), 256, 0, stream>>>(
      xb, 0, E_, wqb, 0, E_, bq, bk, bv,
      Qb, Kb, Vtb, 0, E_, E_, 1.f);

  // P' = exp(Q K^T / 32) (causal, bf16), lower-tri linear grid
  gemm_bt<1><<<dim3(136, 1, 4), 256, 0, stream>>>(
      Qb, (long)S_ * E_, E_, Kb, (long)S_ * E_, E_, nullptr, nullptr, nullptr,
      Pb, nullptr, nullptr, (long)S_ * S_, S_, E_, 0.03125f);

  // out = (P' V) / rowsum(P') : A = P', B = Vt (N=E, K=S), denom via ones-MFMA
  gemm_bt<2><<<dim3(8, 16, 4), 256, 0, stream>>>(
      Pb, (long)S_ * S_, S_,
      Vtb, (long)S_, B_ * S_, nullptr, nullptr, nullptr,
      out, nullptr, nullptr, (long)S_ * E_, E_, S_, 1.f);
}